// Round 11
// baseline (592.935 us; speedup 1.0000x reference)
//
#include <hip/hip_runtime.h>
#include <math.h>

#define N_NODES 50000
#define N_ROWS_PAD 50048   // 782 * 64
#define N_GRAPHS 500
#define NPG 100
#define N_EDGES 500000
#define F_IN 16
#define HID 64
#define EW_CAP_Q 512       // max edges per quarter-graph (mean 250, +16 sigma)
#define EW_CAP_H 1024      // max edges per half-graph

#define SELU_SCALE 1.0507009873554804934193349852946f
#define SELU_ALPHA 1.6732632423543772848170429916717f

typedef __attribute__((ext_vector_type(8))) short short8;
typedef __attribute__((ext_vector_type(4))) float floatx4;

__device__ __forceinline__ float lrelu(float x){ return x > 0.f ? x : 0.2f * x; }
__device__ __forceinline__ float eluf(float x){ return x > 0.f ? x : expf(x) - 1.f; }
__device__ __forceinline__ float seluf(float x){
    return x > 0.f ? SELU_SCALE * x : SELU_SCALE * (SELU_ALPHA * (expf(x) - 1.f));
}
__device__ __forceinline__ unsigned short f2bf(float x){
    unsigned u = __float_as_uint(x);
    return (unsigned short)((u + 0x7FFFu + ((u >> 16) & 1u)) >> 16);
}
__device__ __forceinline__ float bf2f(unsigned short u){
    return __uint_as_float((unsigned)u << 16);
}

// ---------------- CSR build ----------------
__global__ void k_count(const int* __restrict__ dst, int* __restrict__ counts){
    int e = blockIdx.x * 256 + threadIdx.x;
    if (e < N_EDGES) atomicAdd(&counts[dst[e]], 1);
}

__global__ void k_local_scan(const int* __restrict__ counts, int* __restrict__ local_off,
                             int* __restrict__ graph_tot){
    __shared__ int s[128];
    int g = blockIdx.x, t = threadIdx.x;
    int v = (t < NPG) ? counts[g * NPG + t] : 0;
    s[t] = v; __syncthreads();
    for (int o = 1; o < 128; o <<= 1){
        int x = (t >= o) ? s[t - o] : 0;
        __syncthreads();
        s[t] += x;
        __syncthreads();
    }
    if (t < NPG) local_off[g * NPG + t] = s[t] - v;   // exclusive
    if (t == 127) graph_tot[g] = s[127];
}

__global__ void k_graph_scan(const int* __restrict__ graph_tot, int* __restrict__ graph_base){
    __shared__ int s[512];
    int t = threadIdx.x;
    int v = (t < N_GRAPHS) ? graph_tot[t] : 0;
    s[t] = v; __syncthreads();
    for (int o = 1; o < 512; o <<= 1){
        int x = (t >= o) ? s[t - o] : 0;
        __syncthreads();
        s[t] += x;
        __syncthreads();
    }
    if (t < N_GRAPHS) graph_base[t] = s[t] - v;       // exclusive
}

__global__ void k_off(const int* __restrict__ local_off, const int* __restrict__ graph_base,
                      int* __restrict__ node_off, int* __restrict__ write_ptr){
    int n = blockIdx.x * 256 + threadIdx.x;
    if (n < N_NODES){
        int v = local_off[n] + graph_base[n / NPG];
        node_off[n] = v;
        write_ptr[n] = v;
    }
}

__global__ void k_scatter(const int* __restrict__ src, const int* __restrict__ dst,
                          int* __restrict__ write_ptr, int* __restrict__ csr){
    int e = blockIdx.x * 256 + threadIdx.x;
    if (e < N_EDGES){
        int d = dst[e];
        int pos = atomicAdd(&write_ptr[d], 1);
        csr[pos] = src[e];
    }
}

// ---------------- GraphNorm ----------------
__global__ void k_gnorm(const float* __restrict__ x, const float* __restrict__ w,
                        const float* __restrict__ b, const float* __restrict__ ms,
                        float* __restrict__ y){
    __shared__ float sx[NPG * F_IN];
    __shared__ float red[16][16];
    __shared__ float meanS[16], varS[16];
    int g = blockIdx.x, t = threadIdx.x;
    for (int idx = t; idx < NPG * F_IN; idx += 256) sx[idx] = x[g * NPG * F_IN + idx];
    __syncthreads();
    int f = t & 15, grp = t >> 4;
    float p = 0.f;
    for (int i = grp; i < NPG; i += 16) p += sx[i * 16 + f];
    red[grp][f] = p; __syncthreads();
    if (t < 16){
        float s = 0.f;
        for (int i = 0; i < 16; i++) s += red[i][t];
        meanS[t] = s * (1.f / 100.f);
    }
    __syncthreads();
    float mm = meanS[f] * ms[f];
    p = 0.f;
    for (int i = grp; i < NPG; i += 16){ float v = sx[i * 16 + f] - mm; p += v * v; }
    red[grp][f] = p; __syncthreads();
    if (t < 16){
        float s = 0.f;
        for (int i = 0; i < 16; i++) s += red[i][t];
        varS[t] = s * (1.f / 100.f);
    }
    __syncthreads();
    for (int idx = t; idx < NPG * F_IN; idx += 256){
        int ff = idx & 15;
        float v = sx[idx] - meanS[ff] * ms[ff];
        y[g * NPG * F_IN + idx] = w[ff] * v * rsqrtf(varS[ff] + 1e-5f) + b[ff];
    }
}

// ---------------- fp32 tiled GEMM (conv1, K=16), bf16 interleaved OUT ----------------
__global__ void k_gemm_tiled(const float* __restrict__ X, const float* __restrict__ W,
                             unsigned short* __restrict__ Y, int N, int K, int OUT){
    __shared__ float As[16][68];
    __shared__ float Bs[16][68];
    int t = threadIdx.x;
    int r0 = blockIdx.y * 64;
    int c0 = blockIdx.x * 64;
    int tx = t & 15, ty = t >> 4;
    float acc[4][4];
    #pragma unroll
    for (int i = 0; i < 4; i++)
        #pragma unroll
        for (int j = 0; j < 4; j++) acc[i][j] = 0.f;

    int lk = t & 15;
    int lm0 = t >> 4;
    int ln = t & 63;
    int lkb = t >> 6;

    for (int kt = 0; kt < K; kt += 16){
        #pragma unroll
        for (int i = 0; i < 4; i++){
            int m = lm0 + i * 16;
            int row = r0 + m;
            As[lk][m] = (row < N) ? X[row * K + kt + lk] : 0.f;
        }
        #pragma unroll
        for (int i = 0; i < 4; i++){
            int k = lkb + i * 4;
            Bs[k][ln] = W[(kt + k) * OUT + c0 + ln];
        }
        __syncthreads();
        #pragma unroll
        for (int k = 0; k < 16; k++){
            float4 a = *(const float4*)&As[k][ty * 4];
            float4 b = *(const float4*)&Bs[k][tx * 4];
            float av[4] = {a.x, a.y, a.z, a.w};
            float bv[4] = {b.x, b.y, b.z, b.w};
            #pragma unroll
            for (int i = 0; i < 4; i++)
                #pragma unroll
                for (int j = 0; j < 4; j++) acc[i][j] += av[i] * bv[j];
        }
        __syncthreads();
    }
    #pragma unroll
    for (int i = 0; i < 4; i++){
        int row = r0 + ty * 4 + i;
        if (row < N){
            #pragma unroll
            for (int j = 0; j < 4; j++){
                int col = c0 + tx * 4 + j;
                Y[(size_t)row * 256 + (col & 63) * 4 + (col >> 6)] = f2bf(acc[i][j]);
            }
        }
    }
}

// ---------------- W pack: permuted rows (std k=h*64+c -> interleaved k=c*4+h), bf16, MFMA-B order ----
__global__ void k_pack_w_perm(const float* __restrict__ W, unsigned short* __restrict__ Wp,
                              int OUT){
    int idx = blockIdx.x * 256 + threadIdx.x;   // over 256*OUT
    if (idx >= 256 * OUT) return;
    int k_il = idx / OUT, n = idx - k_il * OUT;
    int c = k_il >> 2, hh = k_il & 3;
    int k_std = hh * 64 + c;
    Wp[(((k_il >> 3) * OUT) + n) * 8 + (k_il & 7)] = f2bf(W[k_std * OUT + n]);
}

// ---------------- bf16 MFMA GEMM ----------------
__global__ void k_gemm_mfma(const unsigned short* __restrict__ Xb,
                            const unsigned short* __restrict__ Wp,
                            unsigned short* __restrict__ Ybf, float* __restrict__ Yf,
                            int out_bf16, int N, int K, int OUT){
    int t = threadIdx.x;
    int wave = t >> 6, lane = t & 63;
    int quad = lane >> 4, ln = lane & 15;
    int r0 = blockIdx.y * 64 + wave * 16;
    int c0 = blockIdx.x * 64;

    floatx4 acc[4];
    #pragma unroll
    for (int f = 0; f < 4; f++) acc[f] = (floatx4){0.f, 0.f, 0.f, 0.f};

    const unsigned short* aptr = Xb + (size_t)(r0 + ln) * K + quad * 8;
    for (int kt = 0; kt < K; kt += 32){
        short8 a = *(const short8*)(aptr + kt);
        int kc = (kt >> 3) + quad;
        #pragma unroll
        for (int f = 0; f < 4; f++){
            short8 b = *(const short8*)(Wp + ((size_t)kc * OUT + c0 + f * 16 + ln) * 8);
            acc[f] = __builtin_amdgcn_mfma_f32_16x16x32_bf16(a, b, acc[f], 0, 0, 0);
        }
    }
    int rowb = r0 + quad * 4;
    if (out_bf16){
        #pragma unroll
        for (int f = 0; f < 4; f++){
            int col = c0 + f * 16 + ln;
            int ip = (col & 63) * 4 + (col >> 6);
            #pragma unroll
            for (int rg = 0; rg < 4; rg++){
                int row = rowb + rg;
                if (row < N) Ybf[(size_t)row * 256 + ip] = f2bf(acc[f][rg]);
            }
        }
    } else {
        #pragma unroll
        for (int f = 0; f < 4; f++){
            int col = c0 + f * 16 + ln;
            #pragma unroll
            for (int rg = 0; rg < 4; rg++){
                int row = rowb + rg;
                if (row < N) Yf[(size_t)row * OUT + col] = acc[f][rg];
            }
        }
    }
}

// ---------------- fused GAT layer, FOUR blocks (256 thr) per graph ----------------
// Block q of graph g handles dst in [q*25, q*25+25). Edges for that dst range are a
// contiguous CSR slice. h bf16 head-interleaved [node][c*4+h] streamed from L2.
__global__ void __launch_bounds__(256)
k_fused4(const unsigned short* __restrict__ h, const float* __restrict__ as,
         const float* __restrict__ ad, const float* __restrict__ bias,
         const int* __restrict__ csr, const int* __restrict__ noff,
         const int* __restrict__ cnt, unsigned short* __restrict__ out_bf){
    __shared__ unsigned short csl[EW_CAP_Q];                        // 1024 B
    __shared__ __align__(16) unsigned short ewl[EW_CAP_Q * 4];      // 4096 B
    __shared__ __align__(16) float asrcl[NPG * 4], adstl[NPG * 4];  // 3200 B
    __shared__ __align__(16) float wselfl[25 * 4], rsuml[25 * 4];   // 800 B
    __shared__ int offl[25], cntl[25];                              // 200 B

    int bid = blockIdx.x;
    int g = bid >> 2, q = bid & 3;
    int t = threadIdx.x, wave = t >> 6, lane = t & 63;
    int base = g * NPG;
    int d0 = q * 25;

    int ebeg = noff[base + d0];
    int eend = noff[base + d0 + 24] + cnt[base + d0 + 24];
    int eln = eend - ebeg; if (eln > EW_CAP_Q) eln = EW_CAP_Q;

    // stage CSR slice (localized ids) + per-dst offsets (25 dst)
    for (int i = t; i < eln; i += 256) csl[i] = (unsigned short)(csr[ebeg + i] - base);
    if (t < 25){ offl[t] = noff[base + d0 + t]; cntl[t] = cnt[base + d0 + t]; }

    // logits for ALL 100 nodes (needed as src), one wave per node
    float asr[4], adr[4];
    #pragma unroll
    for (int k = 0; k < 4; k++){ asr[k] = as[k * 64 + lane]; adr[k] = ad[k * 64 + lane]; }
    for (int n = wave; n < NPG; n += 4){
        ushort4 u = *(const ushort4*)(h + (size_t)(base + n) * 256 + lane * 4);
        float hv[4] = {bf2f(u.x), bf2f(u.y), bf2f(u.z), bf2f(u.w)};
        float ps[4], pd[4];
        #pragma unroll
        for (int k = 0; k < 4; k++){ ps[k] = hv[k] * asr[k]; pd[k] = hv[k] * adr[k]; }
        #pragma unroll
        for (int o = 32; o >= 1; o >>= 1){
            #pragma unroll
            for (int k = 0; k < 4; k++){
                ps[k] += __shfl_xor(ps[k], o);
                pd[k] += __shfl_xor(pd[k], o);
            }
        }
        if (lane == 0){
            *(float4*)&asrcl[n * 4] = make_float4(ps[0], ps[1], ps[2], ps[3]);
            *(float4*)&adstl[n * 4] = make_float4(pd[0], pd[1], pd[2], pd[3]);
        }
    }
    __syncthreads();

    // softmax weights: one thread per (dst, head) = 100 threads
    if (t < 100){
        int dq = t >> 2, hh = t & 3;
        int d = d0 + dq;
        float adv = adstl[d * 4 + hh];
        float wsf = expf(lrelu(asrcl[d * 4 + hh] + adv));
        float sum = wsf;
        int ebg = offl[dq] - ebeg, n = cntl[dq];
        for (int j = 0; j < n; j++){
            int s = csl[ebg + j];
            unsigned short u = f2bf(expf(lrelu(asrcl[s * 4 + hh] + adv)));
            ewl[(ebg + j) * 4 + hh] = u;
            sum += bf2f(u);
        }
        wselfl[dq * 4 + hh] = wsf;
        rsuml[dq * 4 + hh] = 1.f / sum;
    }
    __syncthreads();

    // aggregate: one wave per dst node; h rows streamed from L2 (b64/lane)
    float b0 = bias[lane], b1 = bias[64 + lane], b2 = bias[128 + lane], b3 = bias[192 + lane];
    const unsigned short* hb = h + (size_t)base * 256;
    for (int dq = wave; dq < 25; dq += 4){
        int d = d0 + dq;
        float4 ws = *(const float4*)&wselfl[dq * 4];
        float4 rs = *(const float4*)&rsuml[dq * 4];
        ushort4 hv = *(const ushort4*)(hb + (size_t)d * 256 + lane * 4);
        float a0 = ws.x * bf2f(hv.x);
        float a1 = ws.y * bf2f(hv.y);
        float a2 = ws.z * bf2f(hv.z);
        float a3 = ws.w * bf2f(hv.w);
        int ebg = offl[dq] - ebeg, n = cntl[dq];
        int j = 0;
        for (; j + 4 <= n; j += 4){
            int s0 = csl[ebg + j], s1 = csl[ebg + j + 1];
            int s2 = csl[ebg + j + 2], s3 = csl[ebg + j + 3];
            ushort4 w0 = *(const ushort4*)&ewl[(ebg + j) * 4];
            ushort4 w1 = *(const ushort4*)&ewl[(ebg + j + 1) * 4];
            ushort4 w2 = *(const ushort4*)&ewl[(ebg + j + 2) * 4];
            ushort4 w3 = *(const ushort4*)&ewl[(ebg + j + 3) * 4];
            ushort4 x0 = *(const ushort4*)(hb + (size_t)s0 * 256 + lane * 4);
            ushort4 x1 = *(const ushort4*)(hb + (size_t)s1 * 256 + lane * 4);
            ushort4 x2 = *(const ushort4*)(hb + (size_t)s2 * 256 + lane * 4);
            ushort4 x3 = *(const ushort4*)(hb + (size_t)s3 * 256 + lane * 4);
            a0 = fmaf(bf2f(w0.x), bf2f(x0.x), a0);
            a1 = fmaf(bf2f(w0.y), bf2f(x0.y), a1);
            a2 = fmaf(bf2f(w0.z), bf2f(x0.z), a2);
            a3 = fmaf(bf2f(w0.w), bf2f(x0.w), a3);
            a0 = fmaf(bf2f(w1.x), bf2f(x1.x), a0);
            a1 = fmaf(bf2f(w1.y), bf2f(x1.y), a1);
            a2 = fmaf(bf2f(w1.z), bf2f(x1.z), a2);
            a3 = fmaf(bf2f(w1.w), bf2f(x1.w), a3);
            a0 = fmaf(bf2f(w2.x), bf2f(x2.x), a0);
            a1 = fmaf(bf2f(w2.y), bf2f(x2.y), a1);
            a2 = fmaf(bf2f(w2.z), bf2f(x2.z), a2);
            a3 = fmaf(bf2f(w2.w), bf2f(x2.w), a3);
            a0 = fmaf(bf2f(w3.x), bf2f(x3.x), a0);
            a1 = fmaf(bf2f(w3.y), bf2f(x3.y), a1);
            a2 = fmaf(bf2f(w3.z), bf2f(x3.z), a2);
            a3 = fmaf(bf2f(w3.w), bf2f(x3.w), a3);
        }
        for (; j < n; j++){
            int s = csl[ebg + j];
            ushort4 w = *(const ushort4*)&ewl[(ebg + j) * 4];
            ushort4 x = *(const ushort4*)(hb + (size_t)s * 256 + lane * 4);
            a0 = fmaf(bf2f(w.x), bf2f(x.x), a0);
            a1 = fmaf(bf2f(w.y), bf2f(x.y), a1);
            a2 = fmaf(bf2f(w.z), bf2f(x.z), a2);
            a3 = fmaf(bf2f(w.w), bf2f(x.w), a3);
        }
        ushort4 o;
        o.x = f2bf(eluf(a0 * rs.x + b0));
        o.y = f2bf(eluf(a1 * rs.y + b1));
        o.z = f2bf(eluf(a2 * rs.z + b2));
        o.w = f2bf(eluf(a3 * rs.w + b3));
        *(ushort4*)(out_bf + (size_t)(base + d) * 256 + lane * 4) = o;
    }
}

// H=1, C=64, TWO blocks (256 thr) per graph, fp32 in/out, no ELU (conv3 -> head).
__global__ void __launch_bounds__(256)
k_fused1(const float* __restrict__ h, const float* __restrict__ as,
         const float* __restrict__ ad, const float* __restrict__ bias,
         const int* __restrict__ csr, const int* __restrict__ noff,
         const int* __restrict__ cnt, float* __restrict__ out){
    __shared__ __align__(16) unsigned short hl[NPG * 64];  // 12800 B (all 100 srcs)
    __shared__ unsigned short ewl[EW_CAP_H];               // 2048 B
    __shared__ unsigned short csl[EW_CAP_H];               // 2048 B
    __shared__ float asrcl[NPG], adstl[NPG];
    __shared__ float wselfl[50], rsuml[50];
    __shared__ int offl[50], cntl[50];

    int bid = blockIdx.x;
    int g = bid >> 1, q = bid & 1;
    int t = threadIdx.x, wave = t >> 6, lane = t & 63;
    int base = g * NPG;
    int d0 = q * 50;

    int ebeg = noff[base + d0];
    int eend = noff[base + d0 + 49] + cnt[base + d0 + 49];
    int eln = eend - ebeg; if (eln > EW_CAP_H) eln = EW_CAP_H;

    const float4* hsrc = (const float4*)(h + (size_t)base * 64);
    for (int i = t; i < NPG * 16; i += 256){
        float4 v = hsrc[i];
        ushort4 u;
        u.x = f2bf(v.x); u.y = f2bf(v.y); u.z = f2bf(v.z); u.w = f2bf(v.w);
        *(ushort4*)&hl[i * 4] = u;
    }
    for (int i = t; i < eln; i += 256) csl[i] = (unsigned short)(csr[ebeg + i] - base);
    if (t < 50){ offl[t] = noff[base + d0 + t]; cntl[t] = cnt[base + d0 + t]; }

    float asr = as[lane], adr = ad[lane];
    for (int n = wave; n < NPG; n += 4){
        float v = h[(size_t)(base + n) * 64 + lane];
        float ps = v * asr, pd = v * adr;
        #pragma unroll
        for (int o = 32; o >= 1; o >>= 1){
            ps += __shfl_xor(ps, o);
            pd += __shfl_xor(pd, o);
        }
        if (lane == 0){ asrcl[n] = ps; adstl[n] = pd; }
    }
    __syncthreads();

    if (t < 50){
        int d = d0 + t;
        float adv = adstl[d];
        float wsf = expf(lrelu(asrcl[d] + adv));
        float sum = wsf;
        int ebg = offl[t] - ebeg, n = cntl[t];
        for (int j = 0; j < n; j++){
            int s = csl[ebg + j];
            unsigned short u = f2bf(expf(lrelu(asrcl[s] + adv)));
            ewl[ebg + j] = u;
            sum += bf2f(u);
        }
        wselfl[t] = wsf;
        rsuml[t] = 1.f / sum;
    }
    __syncthreads();

    float bl = bias[lane];
    for (int dq = wave; dq < 50; dq += 4){
        int d = d0 + dq;
        float acc = wselfl[dq] * bf2f(hl[d * 64 + lane]);
        int ebg = offl[dq] - ebeg, n = cntl[dq];
        for (int j = 0; j < n; j++){
            int s = csl[ebg + j];
            acc = fmaf(bf2f(ewl[ebg + j]), bf2f(hl[s * 64 + lane]), acc);
        }
        out[(size_t)(base + d) * 64 + lane] = acc * rsuml[dq] + bl;
    }
}

// ---------------- pooling + BN + dense head ----------------
__global__ void k_head(const float* __restrict__ x3, const float* __restrict__ gin,
                       const float* __restrict__ bn_g, const float* __restrict__ bn_b,
                       const float* __restrict__ bn_m, const float* __restrict__ bn_v,
                       const float* __restrict__ Wd1, const float* __restrict__ bd1,
                       const float* __restrict__ Wd2, const float* __restrict__ bd2,
                       const float* __restrict__ Wo, const float* __restrict__ bo,
                       float* __restrict__ out){
    __shared__ float red[256];
    __shared__ float gv[68];
    __shared__ float g2[64];
    __shared__ float g3[64];
    int g = blockIdx.x, t = threadIdx.x;
    int c = t & 63, grp = t >> 6;
    float p = 0.f;
    for (int i = grp; i < NPG; i += 4) p += x3[(g * NPG + i) * 64 + c];
    red[t] = p; __syncthreads();
    if (t < 64){
        float s = red[t] + red[t + 64] + red[t + 128] + red[t + 192];
        float mean = s * (1.f / 100.f);
        gv[t] = (mean - bn_m[t]) * rsqrtf(bn_v[t] + 1e-5f) * bn_g[t] + bn_b[t];
    } else if (t < 68){
        int j = t - 64;
        float v = gin[g * 4 + j];
        gv[t] = (v - bn_m[t]) * rsqrtf(bn_v[t] + 1e-5f) * bn_g[t] + bn_b[t];
    }
    __syncthreads();
    if (t < 64){
        float s = bd1[t];
        for (int i = 0; i < 68; i++) s += gv[i] * Wd1[i * 64 + t];
        g2[t] = seluf(s);
    }
    __syncthreads();
    if (t < 64){
        float s = bd2[t];
        for (int i = 0; i < 64; i++) s += g2[i] * Wd2[i * 64 + t];
        g3[t] = seluf(s);
    }
    __syncthreads();
    if (t == 0){
        float l0 = bo[0], l1 = bo[1];
        for (int i = 0; i < 64; i++){ l0 += g3[i] * Wo[i * 2]; l1 += g3[i] * Wo[i * 2 + 1]; }
        float mx = fmaxf(l0, l1);
        float e0 = expf(l0 - mx), e1 = expf(l1 - mx);
        float inv = 1.f / (e0 + e1);
        out[g * 2] = e0 * inv;
        out[g * 2 + 1] = e1 * inv;
    }
}

extern "C" void kernel_launch(void* const* d_in, const int* in_sizes, int n_in,
                              void* d_out, int out_size, void* d_ws, size_t ws_size,
                              hipStream_t stream){
    const float* x   = (const float*)d_in[0];
    const int*   ei  = (const int*)d_in[1];
    const float* gin = (const float*)d_in[2];
    const float* gn_w = (const float*)d_in[4];
    const float* gn_b = (const float*)d_in[5];
    const float* gn_ms = (const float*)d_in[6];
    const float* W1 = (const float*)d_in[7];
    const float* as1 = (const float*)d_in[8];
    const float* ad1 = (const float*)d_in[9];
    const float* b1 = (const float*)d_in[10];
    const float* W2 = (const float*)d_in[11];
    const float* as2 = (const float*)d_in[12];
    const float* ad2 = (const float*)d_in[13];
    const float* b2 = (const float*)d_in[14];
    const float* W3 = (const float*)d_in[15];
    const float* as3 = (const float*)d_in[16];
    const float* ad3 = (const float*)d_in[17];
    const float* b3 = (const float*)d_in[18];
    const float* bn_g = (const float*)d_in[19];
    const float* bn_b = (const float*)d_in[20];
    const float* bn_m = (const float*)d_in[21];
    const float* bn_v = (const float*)d_in[22];
    const float* Wd1 = (const float*)d_in[23];
    const float* bd1 = (const float*)d_in[24];
    const float* Wd2 = (const float*)d_in[25];
    const float* bd2 = (const float*)d_in[26];
    const float* Wo = (const float*)d_in[27];
    const float* bo = (const float*)d_in[28];
    float* out = (float*)d_out;

    const int* src = ei;
    const int* dst = ei + N_EDGES;

    char* ws = (char*)d_ws;
    size_t off = 0;
    auto alloc = [&](size_t bytes) -> void* {
        void* p = ws + off;
        off = (off + bytes + 255) & ~(size_t)255;
        return p;
    };
    int* counts     = (int*)alloc((size_t)N_NODES * 4);
    int* local_off  = (int*)alloc((size_t)N_NODES * 4);
    int* node_off   = (int*)alloc((size_t)N_NODES * 4);
    int* write_ptr  = (int*)alloc((size_t)N_NODES * 4);
    int* graph_tot  = (int*)alloc(512 * 4);
    int* graph_base = (int*)alloc(512 * 4);
    int* csr        = (int*)alloc((size_t)N_EDGES * 4);
    float* y        = (float*)alloc((size_t)N_NODES * F_IN * 4);
    unsigned short* wp2 = (unsigned short*)alloc((size_t)256 * 256 * 2);
    unsigned short* wp3 = (unsigned short*)alloc((size_t)256 * 64 * 2);
    unsigned short* xh = (unsigned short*)alloc((size_t)N_NODES * 256 * 2);    // GEMM out (bf16 interleaved)
    unsigned short* xb = (unsigned short*)alloc((size_t)N_ROWS_PAD * 256 * 2); // fused out / GEMM in
    float* bufC     = (float*)alloc((size_t)N_NODES * HID * 4);          // conv3 gemm out
    float* bufD     = (float*)alloc((size_t)N_NODES * HID * 4);          // conv3 agg out

    // --- CSR build ---
    hipMemsetAsync(counts, 0, (size_t)N_NODES * 4, stream);
    k_count<<<(N_EDGES + 255) / 256, 256, 0, stream>>>(dst, counts);
    k_local_scan<<<N_GRAPHS, 128, 0, stream>>>(counts, local_off, graph_tot);
    k_graph_scan<<<1, 512, 0, stream>>>(graph_tot, graph_base);
    k_off<<<(N_NODES + 255) / 256, 256, 0, stream>>>(local_off, graph_base, node_off, write_ptr);
    k_scatter<<<(N_EDGES + 255) / 256, 256, 0, stream>>>(src, dst, write_ptr, csr);

    // --- weight packs (bf16, MFMA-B order, rows permuted to interleaved k) ---
    k_pack_w_perm<<<(256 * 256 + 255) / 256, 256, 0, stream>>>(W2, wp2, 256);
    k_pack_w_perm<<<(256 * 64 + 255) / 256, 256, 0, stream>>>(W3, wp3, 64);

    // --- GraphNorm ---
    k_gnorm<<<N_GRAPHS, 256, 0, stream>>>(x, gn_w, gn_b, gn_ms, y);

    dim3 gemm_grid4(4, (N_NODES + 63) / 64);
    dim3 mfma_grid4(4, N_ROWS_PAD / 64);
    dim3 mfma_grid1(1, N_ROWS_PAD / 64);

    // --- conv1: 16 -> 4x64, ELU ---
    k_gemm_tiled<<<gemm_grid4, 256, 0, stream>>>(y, W1, xh, N_NODES, 16, 256);
    k_fused4<<<N_GRAPHS * 4, 256, 0, stream>>>(xh, as1, ad1, b1, csr, node_off, counts, xb);

    // --- conv2: 256 -> 4x64, ELU ---
    k_gemm_mfma<<<mfma_grid4, 256, 0, stream>>>(xb, wp2, xh, nullptr, 1, N_NODES, 256, 256);
    k_fused4<<<N_GRAPHS * 4, 256, 0, stream>>>(xh, as2, ad2, b2, csr, node_off, counts, xb);

    // --- conv3: 256 -> 64, no ELU ---
    k_gemm_mfma<<<mfma_grid1, 256, 0, stream>>>(xb, wp3, nullptr, bufC, 0, N_NODES, 256, 64);
    k_fused1<<<N_GRAPHS * 2, 256, 0, stream>>>(bufC, as3, ad3, b3, csr, node_off, counts, bufD);

    // --- pool + BN + dense head + softmax ---
    k_head<<<N_GRAPHS, 256, 0, stream>>>(bufD, gin, bn_g, bn_b, bn_m, bn_v,
                                         Wd1, bd1, Wd2, bd2, Wo, bo, out);
}

// Round 12
// 415.079 us; speedup vs baseline: 1.4285x; 1.4285x over previous
//
#include <hip/hip_runtime.h>
#include <math.h>

#define N_NODES 50000
#define N_ROWS_PAD 50048   // 782 * 64
#define N_GRAPHS 500
#define NPG 100
#define N_EDGES 500000
#define F_IN 16
#define HID 64
#define EW_CAP 1408
#define AP 136             // LDS row pitch for A / hT (16B-aligned rows, conflict-staggered)

#define SELU_SCALE 1.0507009873554804934193349852946f
#define SELU_ALPHA 1.6732632423543772848170429916717f

typedef __attribute__((ext_vector_type(8))) short short8;
typedef __attribute__((ext_vector_type(4))) float floatx4;

__device__ __forceinline__ float lrelu(float x){ return x > 0.f ? x : 0.2f * x; }
__device__ __forceinline__ float eluf(float x){ return x > 0.f ? x : expf(x) - 1.f; }
__device__ __forceinline__ float seluf(float x){
    return x > 0.f ? SELU_SCALE * x : SELU_SCALE * (SELU_ALPHA * (expf(x) - 1.f));
}
__device__ __forceinline__ unsigned short f2bf(float x){
    unsigned u = __float_as_uint(x);
    return (unsigned short)((u + 0x7FFFu + ((u >> 16) & 1u)) >> 16);
}
__device__ __forceinline__ float bf2f(unsigned short u){
    return __uint_as_float((unsigned)u << 16);
}

// ---------------- CSR build ----------------
__global__ void k_count(const int* __restrict__ dst, int* __restrict__ counts){
    int e = blockIdx.x * 256 + threadIdx.x;
    if (e < N_EDGES) atomicAdd(&counts[dst[e]], 1);
}

__global__ void k_local_scan(const int* __restrict__ counts, int* __restrict__ local_off,
                             int* __restrict__ graph_tot){
    __shared__ int s[128];
    int g = blockIdx.x, t = threadIdx.x;
    int v = (t < NPG) ? counts[g * NPG + t] : 0;
    s[t] = v; __syncthreads();
    for (int o = 1; o < 128; o <<= 1){
        int x = (t >= o) ? s[t - o] : 0;
        __syncthreads();
        s[t] += x;
        __syncthreads();
    }
    if (t < NPG) local_off[g * NPG + t] = s[t] - v;   // exclusive
    if (t == 127) graph_tot[g] = s[127];
}

__global__ void k_graph_scan(const int* __restrict__ graph_tot, int* __restrict__ graph_base){
    __shared__ int s[512];
    int t = threadIdx.x;
    int v = (t < N_GRAPHS) ? graph_tot[t] : 0;
    s[t] = v; __syncthreads();
    for (int o = 1; o < 512; o <<= 1){
        int x = (t >= o) ? s[t - o] : 0;
        __syncthreads();
        s[t] += x;
        __syncthreads();
    }
    if (t < N_GRAPHS) graph_base[t] = s[t] - v;       // exclusive
}

__global__ void k_off(const int* __restrict__ local_off, const int* __restrict__ graph_base,
                      int* __restrict__ node_off, int* __restrict__ write_ptr){
    int n = blockIdx.x * 256 + threadIdx.x;
    if (n < N_NODES){
        int v = local_off[n] + graph_base[n / NPG];
        node_off[n] = v;
        write_ptr[n] = v;
    }
}

__global__ void k_scatter(const int* __restrict__ src, const int* __restrict__ dst,
                          int* __restrict__ write_ptr, int* __restrict__ csr){
    int e = blockIdx.x * 256 + threadIdx.x;
    if (e < N_EDGES){
        int d = dst[e];
        int pos = atomicAdd(&write_ptr[d], 1);
        csr[pos] = src[e];
    }
}

// ---------------- GraphNorm ----------------
__global__ void k_gnorm(const float* __restrict__ x, const float* __restrict__ w,
                        const float* __restrict__ b, const float* __restrict__ ms,
                        float* __restrict__ y){
    __shared__ float sx[NPG * F_IN];
    __shared__ float red[16][16];
    __shared__ float meanS[16], varS[16];
    int g = blockIdx.x, t = threadIdx.x;
    for (int idx = t; idx < NPG * F_IN; idx += 256) sx[idx] = x[g * NPG * F_IN + idx];
    __syncthreads();
    int f = t & 15, grp = t >> 4;
    float p = 0.f;
    for (int i = grp; i < NPG; i += 16) p += sx[i * 16 + f];
    red[grp][f] = p; __syncthreads();
    if (t < 16){
        float s = 0.f;
        for (int i = 0; i < 16; i++) s += red[i][t];
        meanS[t] = s * (1.f / 100.f);
    }
    __syncthreads();
    float mm = meanS[f] * ms[f];
    p = 0.f;
    for (int i = grp; i < NPG; i += 16){ float v = sx[i * 16 + f] - mm; p += v * v; }
    red[grp][f] = p; __syncthreads();
    if (t < 16){
        float s = 0.f;
        for (int i = 0; i < 16; i++) s += red[i][t];
        varS[t] = s * (1.f / 100.f);
    }
    __syncthreads();
    for (int idx = t; idx < NPG * F_IN; idx += 256){
        int ff = idx & 15;
        float v = sx[idx] - meanS[ff] * ms[ff];
        y[g * NPG * F_IN + idx] = w[ff] * v * rsqrtf(varS[ff] + 1e-5f) + b[ff];
    }
}

// ---------------- fp32 tiled GEMM (conv1, K=16), bf16 std OUT ----------------
__global__ void k_gemm_tiled(const float* __restrict__ X, const float* __restrict__ W,
                             unsigned short* __restrict__ Y, int N, int K, int OUT){
    __shared__ float As[16][68];
    __shared__ float Bs[16][68];
    int t = threadIdx.x;
    int r0 = blockIdx.y * 64;
    int c0 = blockIdx.x * 64;
    int tx = t & 15, ty = t >> 4;
    float acc[4][4];
    #pragma unroll
    for (int i = 0; i < 4; i++)
        #pragma unroll
        for (int j = 0; j < 4; j++) acc[i][j] = 0.f;

    int lk = t & 15;
    int lm0 = t >> 4;
    int ln = t & 63;
    int lkb = t >> 6;

    for (int kt = 0; kt < K; kt += 16){
        #pragma unroll
        for (int i = 0; i < 4; i++){
            int m = lm0 + i * 16;
            int row = r0 + m;
            As[lk][m] = (row < N) ? X[row * K + kt + lk] : 0.f;
        }
        #pragma unroll
        for (int i = 0; i < 4; i++){
            int k = lkb + i * 4;
            Bs[k][ln] = W[(kt + k) * OUT + c0 + ln];
        }
        __syncthreads();
        #pragma unroll
        for (int k = 0; k < 16; k++){
            float4 a = *(const float4*)&As[k][ty * 4];
            float4 b = *(const float4*)&Bs[k][tx * 4];
            float av[4] = {a.x, a.y, a.z, a.w};
            float bv[4] = {b.x, b.y, b.z, b.w};
            #pragma unroll
            for (int i = 0; i < 4; i++)
                #pragma unroll
                for (int j = 0; j < 4; j++) acc[i][j] += av[i] * bv[j];
        }
        __syncthreads();
    }
    #pragma unroll
    for (int i = 0; i < 4; i++){
        int row = r0 + ty * 4 + i;
        if (row < N){
            ushort4 u;
            u.x = f2bf(acc[i][0]); u.y = f2bf(acc[i][1]);
            u.z = f2bf(acc[i][2]); u.w = f2bf(acc[i][3]);
            *(ushort4*)&Y[(size_t)row * OUT + c0 + tx * 4] = u;
        }
    }
}

// ---------------- W pack to MFMA-B-fragment order + bf16 ----------------
__global__ void k_pack_w(const float* __restrict__ W, unsigned short* __restrict__ Wp,
                         int K, int OUT){
    int idx = blockIdx.x * 256 + threadIdx.x;
    if (idx >= K * OUT) return;
    int k = idx / OUT, n = idx - k * OUT;
    Wp[(((k >> 3) * OUT) + n) * 8 + (k & 7)] = f2bf(W[idx]);
}

// ---------------- bf16 MFMA GEMM (out: bf16 or fp32) ----------------
__global__ void k_gemm_mfma(const unsigned short* __restrict__ Xb,
                            const unsigned short* __restrict__ Wp,
                            unsigned short* __restrict__ Ybf, float* __restrict__ Yf,
                            int out_bf16, int N, int K, int OUT){
    int t = threadIdx.x;
    int wave = t >> 6, lane = t & 63;
    int quad = lane >> 4, ln = lane & 15;
    int r0 = blockIdx.y * 64 + wave * 16;
    int c0 = blockIdx.x * 64;

    floatx4 acc[4];
    #pragma unroll
    for (int f = 0; f < 4; f++) acc[f] = (floatx4){0.f, 0.f, 0.f, 0.f};

    const unsigned short* aptr = Xb + (size_t)(r0 + ln) * K + quad * 8;
    for (int kt = 0; kt < K; kt += 32){
        short8 a = *(const short8*)(aptr + kt);
        int kc = (kt >> 3) + quad;
        #pragma unroll
        for (int f = 0; f < 4; f++){
            short8 b = *(const short8*)(Wp + ((size_t)kc * OUT + c0 + f * 16 + ln) * 8);
            acc[f] = __builtin_amdgcn_mfma_f32_16x16x32_bf16(a, b, acc[f], 0, 0, 0);
        }
    }
    int rowb = r0 + quad * 4;
    if (out_bf16){
        #pragma unroll
        for (int f = 0; f < 4; f++){
            int col = c0 + f * 16 + ln;
            #pragma unroll
            for (int rg = 0; rg < 4; rg++){
                int row = rowb + rg;
                if (row < N) Ybf[(size_t)row * OUT + col] = f2bf(acc[f][rg]);
            }
        }
    } else {
        #pragma unroll
        for (int f = 0; f < 4; f++){
            int col = c0 + f * 16 + ln;
            #pragma unroll
            for (int rg = 0; rg < 4; rg++){
                int row = rowb + rg;
                if (row < N) Yf[(size_t)row * OUT + col] = acc[f][rg];
            }
        }
    }
}

// ---------------- fused GAT layer via dense-A MFMA, one block (512 thr) per graph ----
// h bf16 std layout [node][head*64+c]. Per head: build A[100(+pad)][100(+pad)] of
// unnormalized softmax weights in LDS (self on diagonal, duplicates accumulated),
// hT = [h_head^T | ones-row]; D = A @ hT gives aggregation (cols 0-63) and fp32
// rowsum (col 64). Normalize + bias + ELU in epilogue. bf16 std out.
__global__ void __launch_bounds__(512)
k_fused4(const unsigned short* __restrict__ h, const float* __restrict__ as,
         const float* __restrict__ ad, const float* __restrict__ bias,
         const int* __restrict__ csr, const int* __restrict__ noff,
         const int* __restrict__ cnt, unsigned short* __restrict__ out_bf){
    __shared__ __align__(16) unsigned short Al[112 * AP];   // 30464 B
    __shared__ __align__(16) unsigned short hT[80 * AP];    // 21760 B
    __shared__ __align__(16) float asrcl[NPG * 4], adstl[NPG * 4];
    __shared__ float rsuml[112];
    __shared__ float biasl[256];
    __shared__ unsigned short csl[EW_CAP];
    __shared__ int offl[NPG], cntl[NPG];

    int g = blockIdx.x, t = threadIdx.x;
    int wave = t >> 6, lane = t & 63;
    int quad = lane >> 4, ln = lane & 15;
    int base = g * NPG;

    int ebeg = noff[base];
    int etot = noff[base + NPG - 1] + cnt[base + NPG - 1] - ebeg;
    int eln = etot < EW_CAP ? etot : EW_CAP;

    // ---- pre-phase: stage csl/offsets/bias, init hT (zeros + ones row), logits ----
    for (int i = t; i < eln; i += 512) csl[i] = (unsigned short)(csr[ebeg + i] - base);
    if (t < NPG){ offl[t] = noff[base + t]; cntl[t] = cnt[base + t]; }
    if (t < 256) biasl[t] = bias[t];
    for (int i = t; i < 80 * AP; i += 512){
        int r = i / AP, c = i - r * AP;
        hT[i] = (r == 64 && c < NPG) ? (unsigned short)0x3F80 : (unsigned short)0;
    }
    // logits: one wave per node, lane = channel
    float asr[4], adr[4];
    #pragma unroll
    for (int k = 0; k < 4; k++){ asr[k] = as[k * 64 + lane]; adr[k] = ad[k * 64 + lane]; }
    for (int n = wave; n < NPG; n += 8){
        const unsigned short* hr = h + (size_t)(base + n) * 256;
        float ps[4], pd[4];
        #pragma unroll
        for (int k = 0; k < 4; k++){
            float v = bf2f(hr[k * 64 + lane]);
            ps[k] = v * asr[k]; pd[k] = v * adr[k];
        }
        #pragma unroll
        for (int o = 32; o >= 1; o >>= 1){
            #pragma unroll
            for (int k = 0; k < 4; k++){
                ps[k] += __shfl_xor(ps[k], o);
                pd[k] += __shfl_xor(pd[k], o);
            }
        }
        if (lane == 0){
            *(float4*)&asrcl[n * 4] = make_float4(ps[0], ps[1], ps[2], ps[3]);
            *(float4*)&adstl[n * 4] = make_float4(pd[0], pd[1], pd[2], pd[3]);
        }
    }
    __syncthreads();

    for (int hh = 0; hh < 4; hh++){
        // ---- P0: zero A + fill hT rows 0..63 with this head's h^T ----
        {
            uint4 z = {0u, 0u, 0u, 0u};
            for (int i = t; i < 112 * AP / 8; i += 512) ((uint4*)Al)[i] = z;
            for (int i = t; i < NPG * 8; i += 512){
                int s = i >> 3, c8 = i & 7;
                ushort4 u0 = *(const ushort4*)(h + (size_t)(base + s) * 256 + hh * 64 + c8 * 8);
                ushort4 u1 = *(const ushort4*)(h + (size_t)(base + s) * 256 + hh * 64 + c8 * 8 + 4);
                hT[(c8 * 8 + 0) * AP + s] = u0.x;
                hT[(c8 * 8 + 1) * AP + s] = u0.y;
                hT[(c8 * 8 + 2) * AP + s] = u0.z;
                hT[(c8 * 8 + 3) * AP + s] = u0.w;
                hT[(c8 * 8 + 4) * AP + s] = u1.x;
                hT[(c8 * 8 + 5) * AP + s] = u1.y;
                hT[(c8 * 8 + 6) * AP + s] = u1.z;
                hT[(c8 * 8 + 7) * AP + s] = u1.w;
            }
        }
        __syncthreads();
        // ---- P1: build A, one thread per dst row (row-private RMW handles duplicates) ----
        if (t < NPG){
            int d = t;
            float adv = adstl[d * 4 + hh];
            float wself = expf(lrelu(asrcl[d * 4 + hh] + adv));
            Al[d * AP + d] = f2bf(wself);
            int ebg = offl[d] - ebeg, n = cntl[d];
            for (int j = 0; j < n; j++){
                int s = csl[ebg + j];
                float w = expf(lrelu(asrcl[s * 4 + hh] + adv));
                unsigned short* p = &Al[d * AP + s];
                *p = f2bf(bf2f(*p) + w);
            }
        }
        __syncthreads();
        // ---- M1: rowsums via ones-column (N-tile 4), waves 0..6 = M-tiles ----
        if (wave < 7){
            int mt = wave;
            floatx4 acc = (floatx4){0.f, 0.f, 0.f, 0.f};
            #pragma unroll
            for (int kc = 0; kc < 4; kc++){
                short8 a = *(const short8*)&Al[(mt * 16 + ln) * AP + kc * 32 + quad * 8];
                short8 b = *(const short8*)&hT[(64 + ln) * AP + kc * 32 + quad * 8];
                acc = __builtin_amdgcn_mfma_f32_16x16x32_bf16(a, b, acc, 0, 0, 0);
            }
            if (ln == 0){
                #pragma unroll
                for (int rg = 0; rg < 4; rg++){
                    int r = mt * 16 + quad * 4 + rg;
                    float v = acc[rg];
                    rsuml[r] = (v > 0.f) ? 1.f / v : 0.f;
                }
            }
        }
        __syncthreads();
        // ---- M2: aggregation tiles (7 M x 4 N), normalize + bias + ELU + store ----
        for (int tt = wave; tt < 28; tt += 8){
            int mt = tt >> 2, nt = tt & 3;
            floatx4 acc = (floatx4){0.f, 0.f, 0.f, 0.f};
            #pragma unroll
            for (int kc = 0; kc < 4; kc++){
                short8 a = *(const short8*)&Al[(mt * 16 + ln) * AP + kc * 32 + quad * 8];
                short8 b = *(const short8*)&hT[(nt * 16 + ln) * AP + kc * 32 + quad * 8];
                acc = __builtin_amdgcn_mfma_f32_16x16x32_bf16(a, b, acc, 0, 0, 0);
            }
            int col = nt * 16 + ln;
            float bl = biasl[hh * 64 + col];
            #pragma unroll
            for (int rg = 0; rg < 4; rg++){
                int r = mt * 16 + quad * 4 + rg;
                if (r < NPG){
                    float o = eluf(acc[rg] * rsuml[r] + bl);
                    out_bf[(size_t)(base + r) * 256 + hh * 64 + col] = f2bf(o);
                }
            }
        }
        __syncthreads();
    }
}

// H=1, C=64, one block (256 thr) per graph, fp32 in/out, no ELU (conv3 -> head).
__global__ void __launch_bounds__(256)
k_fused1(const float* __restrict__ h, const float* __restrict__ as,
         const float* __restrict__ ad, const float* __restrict__ bias,
         const int* __restrict__ csr, const int* __restrict__ noff,
         const int* __restrict__ cnt, float* __restrict__ out){
    __shared__ __align__(16) unsigned short hl[NPG * 64];  // 12800 B
    __shared__ unsigned short ewl[EW_CAP];                 // 2816 B
    __shared__ unsigned short csl[EW_CAP];                 // 2816 B
    __shared__ float asrcl[NPG], adstl[NPG];
    __shared__ float wselfl[NPG], rsuml[NPG];
    __shared__ int offl[NPG], cntl[NPG];

    int g = blockIdx.x, t = threadIdx.x;
    int wave = t >> 6, lane = t & 63;
    int base = g * NPG;

    int ebeg = noff[base];
    int etot = noff[base + NPG - 1] + cnt[base + NPG - 1] - ebeg;
    int eln = etot < EW_CAP ? etot : EW_CAP;

    const float4* hsrc = (const float4*)(h + (size_t)base * 64);
    for (int i = t; i < NPG * 16; i += 256){
        float4 v = hsrc[i];
        ushort4 u;
        u.x = f2bf(v.x); u.y = f2bf(v.y); u.z = f2bf(v.z); u.w = f2bf(v.w);
        *(ushort4*)&hl[i * 4] = u;
    }
    for (int i = t; i < eln; i += 256) csl[i] = (unsigned short)(csr[ebeg + i] - base);
    if (t < NPG){ offl[t] = noff[base + t]; cntl[t] = cnt[base + t]; }

    float asr = as[lane], adr = ad[lane];
    for (int n = wave; n < NPG; n += 4){
        float v = h[(size_t)(base + n) * 64 + lane];
        float ps = v * asr, pd = v * adr;
        #pragma unroll
        for (int o = 32; o >= 1; o >>= 1){
            ps += __shfl_xor(ps, o);
            pd += __shfl_xor(pd, o);
        }
        if (lane == 0){ asrcl[n] = ps; adstl[n] = pd; }
    }
    __syncthreads();

    if (t < NPG){
        float adv = adstl[t];
        float wsf = expf(lrelu(asrcl[t] + adv));
        float sum = wsf;
        int ebg = offl[t] - ebeg, n = cntl[t];
        for (int j = 0; j < n; j++){
            int s = csl[ebg + j];
            unsigned short u = f2bf(expf(lrelu(asrcl[s] + adv)));
            ewl[ebg + j] = u;
            sum += bf2f(u);
        }
        wselfl[t] = wsf;
        rsuml[t] = 1.f / sum;
    }
    __syncthreads();

    float bl = bias[lane];
    for (int d = wave; d < NPG; d += 4){
        float acc = wselfl[d] * bf2f(hl[d * 64 + lane]);
        int ebg = offl[d] - ebeg, n = cntl[d];
        for (int j = 0; j < n; j++){
            int s = csl[ebg + j];
            acc = fmaf(bf2f(ewl[ebg + j]), bf2f(hl[s * 64 + lane]), acc);
        }
        out[(size_t)(base + d) * 64 + lane] = acc * rsuml[d] + bl;
    }
}

// ---------------- pooling + BN + dense head ----------------
__global__ void k_head(const float* __restrict__ x3, const float* __restrict__ gin,
                       const float* __restrict__ bn_g, const float* __restrict__ bn_b,
                       const float* __restrict__ bn_m, const float* __restrict__ bn_v,
                       const float* __restrict__ Wd1, const float* __restrict__ bd1,
                       const float* __restrict__ Wd2, const float* __restrict__ bd2,
                       const float* __restrict__ Wo, const float* __restrict__ bo,
                       float* __restrict__ out){
    __shared__ float red[256];
    __shared__ float gv[68];
    __shared__ float g2[64];
    __shared__ float g3[64];
    int g = blockIdx.x, t = threadIdx.x;
    int c = t & 63, grp = t >> 6;
    float p = 0.f;
    for (int i = grp; i < NPG; i += 4) p += x3[(g * NPG + i) * 64 + c];
    red[t] = p; __syncthreads();
    if (t < 64){
        float s = red[t] + red[t + 64] + red[t + 128] + red[t + 192];
        float mean = s * (1.f / 100.f);
        gv[t] = (mean - bn_m[t]) * rsqrtf(bn_v[t] + 1e-5f) * bn_g[t] + bn_b[t];
    } else if (t < 68){
        int j = t - 64;
        float v = gin[g * 4 + j];
        gv[t] = (v - bn_m[t]) * rsqrtf(bn_v[t] + 1e-5f) * bn_g[t] + bn_b[t];
    }
    __syncthreads();
    if (t < 64){
        float s = bd1[t];
        for (int i = 0; i < 68; i++) s += gv[i] * Wd1[i * 64 + t];
        g2[t] = seluf(s);
    }
    __syncthreads();
    if (t < 64){
        float s = bd2[t];
        for (int i = 0; i < 64; i++) s += g2[i] * Wd2[i * 64 + t];
        g3[t] = seluf(s);
    }
    __syncthreads();
    if (t == 0){
        float l0 = bo[0], l1 = bo[1];
        for (int i = 0; i < 64; i++){ l0 += g3[i] * Wo[i * 2]; l1 += g3[i] * Wo[i * 2 + 1]; }
        float mx = fmaxf(l0, l1);
        float e0 = expf(l0 - mx), e1 = expf(l1 - mx);
        float inv = 1.f / (e0 + e1);
        out[g * 2] = e0 * inv;
        out[g * 2 + 1] = e1 * inv;
    }
}

extern "C" void kernel_launch(void* const* d_in, const int* in_sizes, int n_in,
                              void* d_out, int out_size, void* d_ws, size_t ws_size,
                              hipStream_t stream){
    const float* x   = (const float*)d_in[0];
    const int*   ei  = (const int*)d_in[1];
    const float* gin = (const float*)d_in[2];
    const float* gn_w = (const float*)d_in[4];
    const float* gn_b = (const float*)d_in[5];
    const float* gn_ms = (const float*)d_in[6];
    const float* W1 = (const float*)d_in[7];
    const float* as1 = (const float*)d_in[8];
    const float* ad1 = (const float*)d_in[9];
    const float* b1 = (const float*)d_in[10];
    const float* W2 = (const float*)d_in[11];
    const float* as2 = (const float*)d_in[12];
    const float* ad2 = (const float*)d_in[13];
    const float* b2 = (const float*)d_in[14];
    const float* W3 = (const float*)d_in[15];
    const float* as3 = (const float*)d_in[16];
    const float* ad3 = (const float*)d_in[17];
    const float* b3 = (const float*)d_in[18];
    const float* bn_g = (const float*)d_in[19];
    const float* bn_b = (const float*)d_in[20];
    const float* bn_m = (const float*)d_in[21];
    const float* bn_v = (const float*)d_in[22];
    const float* Wd1 = (const float*)d_in[23];
    const float* bd1 = (const float*)d_in[24];
    const float* Wd2 = (const float*)d_in[25];
    const float* bd2 = (const float*)d_in[26];
    const float* Wo = (const float*)d_in[27];
    const float* bo = (const float*)d_in[28];
    float* out = (float*)d_out;

    const int* src = ei;
    const int* dst = ei + N_EDGES;

    char* ws = (char*)d_ws;
    size_t off = 0;
    auto alloc = [&](size_t bytes) -> void* {
        void* p = ws + off;
        off = (off + bytes + 255) & ~(size_t)255;
        return p;
    };
    int* counts     = (int*)alloc((size_t)N_NODES * 4);
    int* local_off  = (int*)alloc((size_t)N_NODES * 4);
    int* node_off   = (int*)alloc((size_t)N_NODES * 4);
    int* write_ptr  = (int*)alloc((size_t)N_NODES * 4);
    int* graph_tot  = (int*)alloc(512 * 4);
    int* graph_base = (int*)alloc(512 * 4);
    int* csr        = (int*)alloc((size_t)N_EDGES * 4);
    float* y        = (float*)alloc((size_t)N_NODES * F_IN * 4);
    unsigned short* wp2 = (unsigned short*)alloc((size_t)256 * 256 * 2);
    unsigned short* wp3 = (unsigned short*)alloc((size_t)256 * 64 * 2);
    unsigned short* xh = (unsigned short*)alloc((size_t)N_NODES * 256 * 2);    // GEMM out (bf16 std)
    unsigned short* xb = (unsigned short*)alloc((size_t)N_ROWS_PAD * 256 * 2); // fused out / GEMM in
    float* bufC     = (float*)alloc((size_t)N_NODES * HID * 4);          // conv3 gemm out
    float* bufD     = (float*)alloc((size_t)N_NODES * HID * 4);          // conv3 agg out

    // --- CSR build ---
    hipMemsetAsync(counts, 0, (size_t)N_NODES * 4, stream);
    k_count<<<(N_EDGES + 255) / 256, 256, 0, stream>>>(dst, counts);
    k_local_scan<<<N_GRAPHS, 128, 0, stream>>>(counts, local_off, graph_tot);
    k_graph_scan<<<1, 512, 0, stream>>>(graph_tot, graph_base);
    k_off<<<(N_NODES + 255) / 256, 256, 0, stream>>>(local_off, graph_base, node_off, write_ptr);
    k_scatter<<<(N_EDGES + 255) / 256, 256, 0, stream>>>(src, dst, write_ptr, csr);

    // --- weight packs (bf16, MFMA-B order) ---
    k_pack_w<<<(256 * 256 + 255) / 256, 256, 0, stream>>>(W2, wp2, 256, 256);
    k_pack_w<<<(256 * 64 + 255) / 256, 256, 0, stream>>>(W3, wp3, 256, 64);

    // --- GraphNorm ---
    k_gnorm<<<N_GRAPHS, 256, 0, stream>>>(x, gn_w, gn_b, gn_ms, y);

    dim3 gemm_grid4(4, (N_NODES + 63) / 64);
    dim3 mfma_grid4(4, N_ROWS_PAD / 64);
    dim3 mfma_grid1(1, N_ROWS_PAD / 64);

    // --- conv1: 16 -> 4x64, ELU ---
    k_gemm_tiled<<<gemm_grid4, 256, 0, stream>>>(y, W1, xh, N_NODES, 16, 256);
    k_fused4<<<N_GRAPHS, 512, 0, stream>>>(xh, as1, ad1, b1, csr, node_off, counts, xb);

    // --- conv2: 256 -> 4x64, ELU ---
    k_gemm_mfma<<<mfma_grid4, 256, 0, stream>>>(xb, wp2, xh, nullptr, 1, N_NODES, 256, 256);
    k_fused4<<<N_GRAPHS, 512, 0, stream>>>(xh, as2, ad2, b2, csr, node_off, counts, xb);

    // --- conv3: 256 -> 64, no ELU ---
    k_gemm_mfma<<<mfma_grid1, 256, 0, stream>>>(xb, wp3, nullptr, bufC, 0, N_NODES, 256, 64);
    k_fused1<<<N_GRAPHS, 256, 0, stream>>>(bufC, as3, ad3, b3, csr, node_off, counts, bufD);

    // --- pool + BN + dense head + softmax ---
    k_head<<<N_GRAPHS, 256, 0, stream>>>(bufD, gin, bn_g, bn_b, bn_m, bn_v,
                                         Wd1, bd1, Wd2, bd2, Wo, bo, out);
}